// Round 8
// baseline (157.756 us; speedup 1.0000x reference)
//
#include <hip/hip_runtime.h>
#include <stdint.h>

#define TB   256
#define TLEN 2048
#define NB   16
#define NCH  128
#define BN   (NB*NCH)   // 2048 rows
#define KP   6

typedef unsigned long long u64;

__device__ inline float2 cmul(float2 a, float2 b) {
  return make_float2(a.x * b.x - a.y * b.y, a.x * b.y + a.y * b.x);
}
__device__ inline float2 cadd(float2 a, float2 b) { return make_float2(a.x + b.x, a.y + b.y); }
__device__ inline float2 csub(float2 a, float2 b) { return make_float2(a.x - b.x, a.y - b.y); }
__device__ inline float2 cmni(float2 a) { return make_float2(a.y, -a.x); }  // *(-i)

#define PAD(o) ((o) + ((o) >> 4))
#define C2 0.70710678118654752f

// radix-8 butterfly with output twiddles (B[0] untwiddled); w1 = W^cb
__device__ inline void radix8(const float2 A[8], float2 w1, float2 B[8]) {
  float2 s02 = cadd(A[0], A[4]), d02 = csub(A[0], A[4]);
  float2 s13 = cadd(A[2], A[6]), d13 = csub(A[2], A[6]);
  float2 E0 = cadd(s02, s13), E1 = cadd(d02, cmni(d13));
  float2 E2 = csub(s02, s13), E3 = csub(d02, cmni(d13));
  float2 t02 = cadd(A[1], A[5]), e02 = csub(A[1], A[5]);
  float2 t13 = cadd(A[3], A[7]), e13 = csub(A[3], A[7]);
  float2 O0 = cadd(t02, t13), O1 = cadd(e02, cmni(e13));
  float2 O2 = csub(t02, t13), O3 = csub(e02, cmni(e13));
  float2 T0 = O0;
  float2 T1 = make_float2(C2 * (O1.x + O1.y), C2 * (O1.y - O1.x));
  float2 T2 = cmni(O2);
  float2 T3 = make_float2(C2 * (O3.y - O3.x), -C2 * (O3.x + O3.y));
  float2 b0 = cadd(E0, T0), b4 = csub(E0, T0);
  float2 b1 = cadd(E1, T1), b5 = csub(E1, T1);
  float2 b2 = cadd(E2, T2), b6 = csub(E2, T2);
  float2 b3 = cadd(E3, T3), b7 = csub(E3, T3);
  float2 w2 = cmul(w1, w1);
  float2 w3 = cmul(w2, w1);
  float2 w4 = cmul(w2, w2);
  float2 w5 = cmul(w4, w1);
  float2 w6 = cmul(w4, w2);
  float2 w7 = cmul(w4, w3);
  B[0] = b0;
  B[1] = cmul(w1, b1);
  B[2] = cmul(w2, b2);
  B[3] = cmul(w3, b3);
  B[4] = cmul(w4, b4);
  B[5] = cmul(w5, b5);
  B[6] = cmul(w6, b6);
  B[7] = cmul(w7, b7);
}

// ---------------------------------------------------------------------------
// K0: transpose x[b][t][n] -> seqs[(b*NCH+n)][t]  (1024 tiles of 64x64)
// ---------------------------------------------------------------------------
__global__ __launch_bounds__(256) void k_transpose(const float* __restrict__ x,
                                                   float* __restrict__ seqs) {
  __shared__ float tile[64][65];
  int bid = blockIdx.x;
  int tb = bid & 31, nb = (bid >> 5) & 1, b = bid >> 6;
  int t0 = tb * 64, n0 = nb * 64;
  int tx = threadIdx.x & 63, ty = threadIdx.x >> 6;
#pragma unroll
  for (int tt = ty; tt < 64; tt += 4)
    tile[tt][tx] = x[(size_t)(b * TLEN + t0 + tt) * NCH + n0 + tx];
  __syncthreads();
#pragma unroll
  for (int nn = ty; nn < 64; nn += 4)
    seqs[(size_t)(b * NCH + n0 + nn) * TLEN + t0 + tx] = tile[tx][nn];
}

// ---------------------------------------------------------------------------
// K1: two-for-one real FFT (radix-8 x3 + radix-4, Stockham, padded LDS)
//     + LDS-key top-6 + fold into compact seg runs + Pg.
// __launch_bounds__(256,4): VGPR<=128 so LDS (37KB -> 4 blocks/CU) is the
// binding limit = 16 waves/CU guaranteed.
// ---------------------------------------------------------------------------
__global__ __launch_bounds__(256, 4) void k_fft_fold(const float* __restrict__ seqs,
                                                     float* __restrict__ seg,
                                                     int* __restrict__ Pg) {
  __shared__ __align__(16) float2 bufA[2176];   // spectrum ends here; then keys
  __shared__ __align__(16) float2 bufB[2176];   // raw rows reloaded here post-FFT
  __shared__ float2 tw[256];                    // W_2048^j, j<256
  __shared__ u64 wmax[4];
  __shared__ int4 prm[2][KP];
  int tid = threadIdx.x, lane = tid & 63, wv = tid >> 6;
  int r0 = blockIdx.x * 2;
  const float* row0 = seqs + (size_t)r0 * TLEN;

  // load rows 2r, 2r+1 as (re, im) — coalesced from seqs
#pragma unroll
  for (int kk = 0; kk < 8; kk++) {
    int t = tid + kk * TB;
    bufA[PAD(t)] = make_float2(row0[t], row0[t + TLEN]);
  }
  {
    float sn, cs;
    sincosf((-6.283185307179586f / 2048.f) * (float)tid, &sn, &cs);
    tw[tid & 255] = make_float2(cs, sn);
  }

  // 3 radix-8 stages: s=1 (A->B), s=8 (B->A), s=64 (A->B)
#pragma unroll
  for (int stage = 0; stage < 3; stage++) {
    int s = (stage == 0) ? 1 : (stage == 1) ? 8 : 64;
    float2* xb = (stage == 1) ? bufB : bufA;
    float2* yb = (stage == 1) ? bufA : bufB;
    __syncthreads();
    int i = tid;
    int q = i & (s - 1);
    int cb = i - q;
    float2 A[8], B[8];
#pragma unroll
    for (int j = 0; j < 8; j++) A[j] = xb[PAD(i + j * 256)];
    radix8(A, tw[cb], B);
    int o = q + 8 * cb;
#pragma unroll
    for (int j = 0; j < 8; j++) yb[PAD(o + j * s)] = B[j];
  }
  // final radix-4 (s=512, twiddle-free): B -> A ; spectrum lands in bufA
  __syncthreads();
#pragma unroll
  for (int ii = 0; ii < 2; ii++) {
    int i = tid + ii * TB;       // [0,512)
    float2 a0 = bufB[PAD(i)], a1 = bufB[PAD(i + 512)];
    float2 a2 = bufB[PAD(i + 1024)], a3 = bufB[PAD(i + 1536)];
    float2 S02 = cadd(a0, a2), D02 = csub(a0, a2);
    float2 S13 = cadd(a1, a3), D13 = csub(a1, a3);
    bufA[PAD(i)]        = cadd(S02, S13);
    bufA[PAD(i + 512)]  = cadd(D02, cmni(D13));
    bufA[PAD(i + 1024)] = csub(S02, S13);
    bufA[PAD(i + 1536)] = csub(D02, cmni(D13));
  }
  __syncthreads();

  // keys: compute in regs from spectrum (bufA), then overwrite bufA with keys
  u64 kra[4], krb[4];
#pragma unroll
  for (int ii = 0; ii < 4; ii++) {
    int i = tid + ii * TB;       // [0,1024)
    int kb = i + 1;
    float2 zk = bufA[PAD(kb)];
    float2 zc = bufA[PAD(2048 - kb)];
    float ax = zk.x + zc.x, ay = zk.y - zc.y;   // 2*X[kb]
    float bx = zk.x - zc.x, by = zk.y + zc.y;   // 2i*Y[kb]
    float m2a = ax * ax + ay * ay;              // const scale, order-safe
    float m2b = bx * bx + by * by;
    kra[ii] = ((u64)__float_as_uint(m2a) << 32) | (unsigned)(0xFFFFFFFFu - (unsigned)kb);
    krb[ii] = ((u64)__float_as_uint(m2b) << 32) | (unsigned)(0xFFFFFFFFu - (unsigned)kb);
  }
  __syncthreads();   // all spectrum reads done
  u64* keys = (u64*)bufA;        // [0..1023]=row r0, [1024..2047]=row r0+1
#pragma unroll
  for (int ii = 0; ii < 4; ii++) {
    int i = tid + ii * TB;
    keys[i] = kra[ii];
    keys[1024 + i] = krb[ii];
  }
  // reload raw rows (L2/L3-hot) into dead bufB; overlaps topk via vmcnt
  {
    const float4* s4 = (const float4*)row0;
    float4* r4 = (float4*)bufB;
#pragma unroll
    for (int ii = 0; ii < 4; ii++) r4[tid + ii * TB] = s4[tid + ii * TB];
  }
  __syncthreads();

  // top-6: waves 0-1 own row r0, waves 2-3 own row r0+1
  int rw2 = wv >> 1;
  u64* kb2 = keys + rw2 * 1024;
  int t2 = tid & 127;
  for (int r = 0; r < KP; r++) {
    u64 best = 0ull;
    for (int i = t2; i < 1024; i += 128) {
      u64 v = kb2[i];
      best = v > best ? v : best;
    }
    for (int off = 32; off > 0; off >>= 1) {
      u64 o = __shfl_down(best, off);
      best = o > best ? o : best;
    }
    if (lane == 0) wmax[wv] = best;
    __syncthreads();
    if (t2 == 0) {
      u64 b0 = wmax[rw2 * 2], b1 = wmax[rw2 * 2 + 1];
      best = b0 > b1 ? b0 : b1;
      int bin = (int)(0xFFFFFFFFu - (unsigned)(best & 0xFFFFFFFFull));
      if (bin < 1 || bin > 1024) bin = 1;
      kb2[bin - 1] = 0ull;
      int P = TLEN / bin;
      int cyc = TLEN / P;
      int base = TLEN - cyc * P;
      prm[rw2][r] = make_int4(P, base, cyc, 0);
      Pg[(r0 + rw2) * KP + r] = P;
    }
    __syncthreads();
  }

  // fold: 12 (row,k) tasks over 4 waves; compact contiguous runs to seg
  float* srows = (float*)bufB;
  for (int task = wv; task < 2 * KP; task += 4) {
    int rw = task & 1, k = task >> 1;
    int4 pr = prm[rw][k];
    int P = pr.x, base = pr.y, cyc = pr.z;
    float inv = 1.0f / (float)cyc;
    const float* srow = srows + rw * TLEN;
    float* dst = seg + ((size_t)(r0 + rw) * KP + k) * TLEN;

    if (P >= 64) {
      for (int p = lane; p < P; p += 64) {
        const float* sp = srow + base + p;
        float s = 0.f;
        for (int c = 0; c < cyc; c++) s += sp[c * P];
        dst[p] = s * inv;
      }
    } else {
      int wc = 64 / P, u = wc * P, ci = lane / P;
      float v = 0.f;
      if (lane < u) {
        for (int c0 = 0; c0 < cyc; c0 += wc) {
          int c = c0 + ci;
          if (c < cyc) v += srow[base + c0 * P + lane];
        }
      }
      for (int s = P; s < u; s <<= 1) {
        float o = __shfl_down(v, s);
        if (lane + s < u) v += o;
      }
      if (lane < P) dst[lane] = v * inv;
    }
  }
}

// ---------------------------------------------------------------------------
// K2: expand — write ALL of out (zeros + values) as coalesced float4 streams,
// with a pure-zero fast path for p-chunks beyond Pmax(b,k).
// block z: pc = z&15 (128-p chunk), bk = z>>4. out[((b*KP+k)*TLEN+p)*NCH+n]
// ---------------------------------------------------------------------------
__global__ __launch_bounds__(256) void k_expand(const float* __restrict__ seg,
                                                const int* __restrict__ Pg,
                                                float4* __restrict__ out4) {
  __shared__ int Parr[NCH];
  __shared__ int Pmax_s;
  int z = blockIdx.x;
  int pc = z & 15, bk = z >> 4;
  int b = bk / KP, k = bk - KP * b;
  int tid = threadIdx.x;
  if (tid < NCH) Parr[tid] = Pg[(b * NCH + tid) * KP + k];
  __syncthreads();
  if (tid < 64) {
    int m = max(Parr[tid], Parr[tid + 64]);
    for (int off = 32; off > 0; off >>= 1) {
      int o = __shfl_down(m, off);
      m = o > m ? o : m;
    }
    if (tid == 0) Pmax_s = m;
  }
  __syncthreads();
  int p0 = pc * 128;
  int Pmax = Pmax_s;
  float4 z4 = make_float4(0.f, 0.f, 0.f, 0.f);
  size_t obase = (size_t)bk * TLEN * (NCH / 4);
  if (p0 >= Pmax) {
    for (int e = tid; e < 4096; e += TB)
      out4[obase + (size_t)(p0 + (e >> 5)) * (NCH / 4) + (e & 31)] = z4;
  } else {
    for (int e = tid; e < 4096; e += TB) {
      int p = p0 + (e >> 5);
      float4 v = z4;
      if (p < Pmax) {
        int n4 = (e & 31) * 4;
        float* vp = &v.x;
#pragma unroll
        for (int c = 0; c < 4; c++) {
          int n = n4 + c;
          if (p < Parr[n])
            vp[c] = seg[((size_t)(b * NCH + n) * KP + k) * TLEN + p];
        }
      }
      out4[obase + (size_t)p * (NCH / 4) + (e & 31)] = v;
    }
  }
}

// ---------------------------------------------------------------------------
extern "C" void kernel_launch(void* const* d_in, const int* in_sizes, int n_in,
                              void* d_out, int out_size, void* d_ws, size_t ws_size,
                              hipStream_t stream) {
  const float* x = (const float*)d_in[0];
  float* out = (float*)d_out;
  char* ws = (char*)d_ws;

  const size_t seqs_bytes = (size_t)BN * TLEN * 4;       // 16.8 MB
  const size_t seg_bytes  = (size_t)BN * KP * TLEN * 4;  // 100.7 MB
  float* seqs = (float*)ws;
  float* seg  = (float*)(ws + seqs_bytes);
  int* Pg     = (int*)(ws + seqs_bytes + seg_bytes);     // 48 KB

  k_transpose<<<1024, 256, 0, stream>>>(x, seqs);
  k_fft_fold<<<BN / 2, 256, 0, stream>>>(seqs, seg, Pg);
  k_expand<<<NB * KP * 16, 256, 0, stream>>>(seg, Pg, (float4*)out);
}

// Round 9
// 145.959 us; speedup vs baseline: 1.0808x; 1.0808x over previous
//
#include <hip/hip_runtime.h>
#include <stdint.h>

#define TB   256
#define FT   512
#define TLEN 2048
#define NB   16
#define NCH  128
#define BN   (NB*NCH)   // 2048 rows
#define KP   6

typedef unsigned long long u64;

__device__ inline float2 cmul(float2 a, float2 b) {
  return make_float2(a.x * b.x - a.y * b.y, a.x * b.y + a.y * b.x);
}
__device__ inline float2 cadd(float2 a, float2 b) { return make_float2(a.x + b.x, a.y + b.y); }
__device__ inline float2 csub(float2 a, float2 b) { return make_float2(a.x - b.x, a.y - b.y); }
__device__ inline float2 cmni(float2 a) { return make_float2(a.y, -a.x); }  // *(-i)

#define PAD(o) ((o) + ((o) >> 4))

// ---------------------------------------------------------------------------
// K0: fused zero-fill(out) + transpose x[b][t][n] -> seqs[(b*NCH+n)][t]
// blocks [0,1024): transpose tiles; blocks [1024,...): fill out
// ---------------------------------------------------------------------------
__global__ __launch_bounds__(256) void k_prep(const float* __restrict__ x,
                                              float* __restrict__ seqs,
                                              float4* __restrict__ out4, int n4) {
  int bid = blockIdx.x;
  if (bid < 1024) {
    __shared__ float tile[64][65];
    int tb = bid & 31, nb = (bid >> 5) & 1, b = bid >> 6;
    int t0 = tb * 64, n0 = nb * 64;
    int tx = threadIdx.x & 63, ty = threadIdx.x >> 6;
#pragma unroll
    for (int tt = ty; tt < 64; tt += 4)
      tile[tt][tx] = x[(size_t)(b * TLEN + t0 + tt) * NCH + n0 + tx];
    __syncthreads();
#pragma unroll
    for (int nn = ty; nn < 64; nn += 4)
      seqs[(size_t)(b * NCH + n0 + nn) * TLEN + t0 + tx] = tile[tx][nn];
  } else {
    int i = (bid - 1024) * 256 + threadIdx.x;
    if (i < n4) out4[i] = make_float4(0.f, 0.f, 0.f, 0.f);
  }
}

// ---------------------------------------------------------------------------
// K1: two-for-one real FFT, radix-4 x5 + radix-2 Stockham (R4-verified
// indexing), 512 threads / 1 butterfly per thread per stage.
// LDS ~39 KB -> 4 blocks/CU x 8 waves = 32 waves/CU (full occupancy).
// launch_bounds(512,8) caps VGPR at 64 to guarantee it.
// Then per-wave-group top-6 + per-wave fold scattered into pre-zeroed out.
// ---------------------------------------------------------------------------
__global__ __launch_bounds__(FT, 8) void k_fft_fold(const float* __restrict__ seqs,
                                                    float* __restrict__ out) {
  __shared__ __align__(16) float2 bufA[2176];   // spectrum ends here; then keys
  __shared__ __align__(16) float2 bufB[2176];   // raw rows reloaded post-FFT
  __shared__ float2 tw[512];                    // W_2048^j, j<512
  __shared__ u64 wmax[8];
  __shared__ int4 prm[2][KP];
  int tid = threadIdx.x, lane = tid & 63, wv = tid >> 6;
  int r0 = blockIdx.x * 2;
  const float* row0 = seqs + (size_t)r0 * TLEN;

  // load rows 2r, 2r+1 as (re, im) — coalesced
#pragma unroll
  for (int kk = 0; kk < 4; kk++) {
    int t = tid + kk * FT;
    bufA[PAD(t)] = make_float2(row0[t], row0[t + TLEN]);
  }
  {
    float sn, cs;
    sincosf((-6.283185307179586f / 2048.f) * (float)tid, &sn, &cs);
    tw[tid & 511] = make_float2(cs, sn);
  }

  // 5 radix-4 stages: s = 1,4,16,64,256 ; A->B->A->B->A->B
  float2* xb = bufA;
  float2* yb = bufB;
#pragma unroll
  for (int st2 = 0; st2 < 10; st2 += 2) {
    int s = 1 << st2;
    __syncthreads();
    int i = tid;                       // [0,512)
    int q = i & (s - 1);
    int cb = i - q;                    // c*s < 512
    float2 A0 = xb[PAD(i)];
    float2 A1 = xb[PAD(i + 512)];
    float2 A2 = xb[PAD(i + 1024)];
    float2 A3 = xb[PAD(i + 1536)];
    float2 S02 = cadd(A0, A2), D02 = csub(A0, A2);
    float2 S13 = cadd(A1, A3), D13 = csub(A1, A3);
    float2 b0 = cadd(S02, S13);
    float2 b1 = cadd(D02, cmni(D13));
    float2 b2 = csub(S02, S13);
    float2 b3 = csub(D02, cmni(D13));
    float2 w1 = tw[cb];
    float2 w2 = cmul(w1, w1);
    float2 w3 = cmul(w1, w2);
    int o = q + 4 * cb;
    yb[PAD(o)]         = b0;
    yb[PAD(o + s)]     = cmul(w1, b1);
    yb[PAD(o + 2 * s)] = cmul(w2, b2);
    yb[PAD(o + 3 * s)] = cmul(w3, b3);
    float2* t2 = xb; xb = yb; yb = t2;
  }
  // final radix-2 (s=1024, twiddle-free): B -> A ; spectrum lands in bufA
  __syncthreads();
#pragma unroll
  for (int ii = 0; ii < 2; ii++) {
    int i = tid + ii * FT;             // [0,1024)
    float2 a = bufB[PAD(i)];
    float2 b = bufB[PAD(i + 1024)];
    bufA[PAD(i)]        = cadd(a, b);
    bufA[PAD(i + 1024)] = csub(a, b);
  }
  __syncthreads();

  // keys from spectrum (regs), then overwrite bufA with keys
  u64 kra[2], krb[2];
#pragma unroll
  for (int ii = 0; ii < 2; ii++) {
    int i = tid + ii * FT;             // [0,1024)
    int kb = i + 1;
    float2 zk = bufA[PAD(kb)];
    float2 zc = bufA[PAD(2048 - kb)];
    float ax = zk.x + zc.x, ay = zk.y - zc.y;   // 2*X[kb]
    float bx = zk.x - zc.x, by = zk.y + zc.y;   // 2i*Y[kb]
    float m2a = ax * ax + ay * ay;              // const scale, order-safe
    float m2b = bx * bx + by * by;
    kra[ii] = ((u64)__float_as_uint(m2a) << 32) | (unsigned)(0xFFFFFFFFu - (unsigned)kb);
    krb[ii] = ((u64)__float_as_uint(m2b) << 32) | (unsigned)(0xFFFFFFFFu - (unsigned)kb);
  }
  __syncthreads();   // all spectrum reads done
  u64* keys = (u64*)bufA;              // [0..1023]=row r0, [1024..2047]=row r0+1
#pragma unroll
  for (int ii = 0; ii < 2; ii++) {
    int i = tid + ii * FT;
    keys[i] = kra[ii];
    keys[1024 + i] = krb[ii];
  }
  // reload raw rows (L2-hot) into dead bufB
  {
    const float4* s4 = (const float4*)row0;
    float4* r4 = (float4*)bufB;
#pragma unroll
    for (int ii = 0; ii < 2; ii++) r4[tid + ii * FT] = s4[tid + ii * FT];
  }
  __syncthreads();

  // top-6: waves 0-3 own row r0, waves 4-7 own row r0+1
  int rw2 = wv >> 2;
  u64* kb2 = keys + rw2 * 1024;
  int t2 = tid & 255;
  for (int r = 0; r < KP; r++) {
    u64 best = 0ull;
#pragma unroll
    for (int j = 0; j < 4; j++) {
      u64 v = kb2[t2 + j * 256];
      best = v > best ? v : best;
    }
    for (int off = 32; off > 0; off >>= 1) {
      u64 o = __shfl_down(best, off);
      best = o > best ? o : best;
    }
    if (lane == 0) wmax[wv] = best;
    __syncthreads();
    if (t2 == 0) {
      best = wmax[rw2 * 4];
#pragma unroll
      for (int w = 1; w < 4; w++) {
        u64 v = wmax[rw2 * 4 + w];
        best = v > best ? v : best;
      }
      int bin = (int)(0xFFFFFFFFu - (unsigned)(best & 0xFFFFFFFFull));
      if (bin < 1 || bin > 1024) bin = 1;
      kb2[bin - 1] = 0ull;
      int P = TLEN / bin;
      int cyc = TLEN / P;
      int base = TLEN - cyc * P;
      prm[rw2][r] = make_int4(P, base, cyc, 0);
    }
    __syncthreads();
  }

  // fold: 12 (row,k) tasks over 8 waves; scatter into pre-zeroed out
  float* srows = (float*)bufB;
  for (int task = wv; task < 2 * KP; task += 8) {
    int rw = task & 1, k = task >> 1;
    int4 pr = prm[rw][k];
    int P = pr.x, base = pr.y, cyc = pr.z;
    float inv = 1.0f / (float)cyc;
    const float* srow = srows + rw * TLEN;
    int row = r0 + rw, b = row >> 7, n = row & 127;
    float* dst = out + (size_t)(b * KP + k) * TLEN * NCH + n;

    if (P >= 64) {
      for (int p = lane; p < P; p += 64) {
        const float* sp = srow + base + p;
        float s = 0.f;
        for (int c = 0; c < cyc; c++) s += sp[c * P];
        dst[(size_t)p * NCH] = s * inv;
      }
    } else {
      int wc = 64 / P, u = wc * P, ci = lane / P;
      float v = 0.f;
      if (lane < u) {
        for (int c0 = 0; c0 < cyc; c0 += wc) {
          int c = c0 + ci;
          if (c < cyc) v += srow[base + c0 * P + lane];
        }
      }
      for (int s = P; s < u; s <<= 1) {
        float o = __shfl_down(v, s);
        if (lane + s < u) v += o;
      }
      if (lane < P) dst[(size_t)lane * NCH] = v * inv;
    }
  }
}

// ---------------------------------------------------------------------------
extern "C" void kernel_launch(void* const* d_in, const int* in_sizes, int n_in,
                              void* d_out, int out_size, void* d_ws, size_t ws_size,
                              hipStream_t stream) {
  const float* x = (const float*)d_in[0];
  float* out = (float*)d_out;
  float* seqs = (float*)d_ws;                    // 16.8 MB

  int n4 = out_size / 4;
  int fill_blocks = (n4 + 255) / 256;
  k_prep<<<1024 + fill_blocks, 256, 0, stream>>>(x, seqs, (float4*)out, n4);
  k_fft_fold<<<BN / 2, FT, 0, stream>>>(seqs, out);
}